// Round 5
// baseline (568.415 us; speedup 1.0000x reference)
//
#include <hip/hip_runtime.h>
#include <hip/hip_bf16.h>
#include <stdint.h>

// StyleGAN2 style block. B=8, H=W=64, Cin=Cout=512, wdim=512.
// Dtype-adaptive via sniff of style_bias[0].
// k_conv v5: A halo in LDS (33.8 KB, staged once per 64-ch chunk, 2 barriers
// per chunk = 16/block). B read DIRECTLY from global (wkt) into registers:
// each MFMA B-fragment is 16 contiguous bytes of a wkt row -> one
// global_load_dwordx4, software-pipelined at half-tap distance (two 4-frag
// register sets). No B LDS, no B barriers, no bank conflicts. 288 MFMAs per
// barrier interval.

typedef __attribute__((ext_vector_type(8))) __bf16 bf16x8;
typedef __attribute__((ext_vector_type(4))) float f32x4;

__device__ __forceinline__ float bf2f(ushort u) {
    union { uint32_t i; float f; } v; v.i = (uint32_t)u << 16; return v.f;
}
__device__ __forceinline__ ushort f2bf(float f) {
    union { float f; uint32_t i; } v; v.f = f;
    uint32_t r = v.i + 0x7fffu + ((v.i >> 16) & 1u);
    return (ushort)(r >> 16);
}
__device__ __forceinline__ int sniff_f32(const void* sb) {
    return ((const uint32_t*)sb)[0] == 0x3F800000u;
}
__device__ __forceinline__ float lda(const void* p, int idx, int isf) {
    return isf ? ((const float*)p)[idx] : bf2f(((const ushort*)p)[idx]);
}

union U16x8 { uint4 v; ushort u[8]; };

#define INV_SQRT_WDIM 0.04419417382415922f   /* 1/sqrt(512) */
#define SQRT2         1.4142135623730951f
#define WSCALE        0.014731391274719739f  /* 1/sqrt(9*512) */

// ---------------- style FC, split-K: part[b][ds][i] -----------------------
__global__ void k_style_part(const void* __restrict__ w, const void* __restrict__ sw,
                             const void* __restrict__ sb, float* __restrict__ part) {
    int isf = sniff_f32(sb);
    int b = blockIdx.x >> 3, ds = blockIdx.x & 7;   // 64 blocks
    int i = threadIdx.x;                             // 512 threads
    __shared__ float wrow[64];
    if (i < 64) wrow[i] = lda(w, b * 512 + ds * 64 + i, isf);
    __syncthreads();
    float acc = 0.f;
    if (isf) {
        const float* p = (const float*)sw + (size_t)ds * 64 * 512;
#pragma unroll 8
        for (int d = 0; d < 64; ++d) acc += wrow[d] * p[d * 512 + i];
    } else {
        const ushort* p = (const ushort*)sw + (size_t)ds * 64 * 512;
#pragma unroll 8
        for (int d = 0; d < 64; ++d) acc += wrow[d] * bf2f(p[d * 512 + i]);
    }
    part[(b * 8 + ds) * 512 + i] = acc;
}

__global__ void k_style_fin(const float* __restrict__ part, const void* __restrict__ sb,
                            float* __restrict__ s_out) {
    int isf = sniff_f32(sb);
    int b = blockIdx.x, i = threadIdx.x;             // 8 x 512
    float a = 0.f;
#pragma unroll
    for (int ds = 0; ds < 8; ++ds) a += part[(b * 8 + ds) * 512 + i];
    float s = a * INV_SQRT_WDIM + lda(sb, i, isf);
    s = (s > 0.f ? s : 0.2f * s) * SQRT2;
    s_out[b * 512 + i] = s;
}

// ---------------- padded modulated input: xmp[b][66][66][512] bf16 ---------
__global__ void k_pad(const void* __restrict__ x, const float* __restrict__ s,
                      const void* __restrict__ sb, ushort* __restrict__ xmp) {
    int isf = sniff_f32(sb);
    int pr = blockIdx.x;                       // 8*66 blocks
    int b = pr / 66, yp = pr % 66;
    int tid = threadIdx.x;                     // 256 threads
    ushort* rowp = xmp + ((size_t)b * 66 + yp) * 66 * 512;
    uint4 z = {0u, 0u, 0u, 0u};
    if (yp == 0 || yp == 65) {
        uint4* p = (uint4*)rowp;
        for (int l = tid; l < 66 * 512 * 2 / 16; l += 256) p[l] = z;
        return;
    }
    __shared__ float sv[512];
    for (int c = tid; c < 512; c += 256) sv[c] = s[b * 512 + c];
    if (tid < 64)       ((uint4*)rowp)[tid] = z;
    else if (tid < 128) ((uint4*)(rowp + 65 * 512))[tid - 64] = z;
    __syncthreads();
    int y = yp - 1;
    ushort* xout = rowp + 512;
    if (isf) {
        const float* xin = (const float*)x + ((size_t)b * 64 + y) * 64 * 512;
        for (int l = tid; l < 8192; l += 256) {
            int xi = l >> 7, cc = (l & 127) * 4;
            float4 in = *(const float4*)(xin + (size_t)xi * 512 + cc);
            ushort4 ov;
            ov.x = f2bf(in.x * sv[cc + 0]);
            ov.y = f2bf(in.y * sv[cc + 1]);
            ov.z = f2bf(in.z * sv[cc + 2]);
            ov.w = f2bf(in.w * sv[cc + 3]);
            *(ushort4*)(xout + (size_t)xi * 512 + cc) = ov;
        }
    } else {
        const ushort* xin = (const ushort*)x + ((size_t)b * 64 + y) * 64 * 512;
        for (int l = tid; l < 4096; l += 256) {
            int xi = l >> 6, cc = (l & 63) * 8;
            U16x8 in, ov;
            in.v = *(const uint4*)(xin + (size_t)xi * 512 + cc);
#pragma unroll
            for (int j = 0; j < 8; ++j) ov.u[j] = f2bf(bf2f(in.u[j]) * sv[cc + j]);
            *(uint4*)(xout + (size_t)xi * 512 + cc) = ov.v;
        }
    }
}

// ---------------- WkT[t][o][i] = cw[t][i][o] * 1/sqrt(4608), bf16 ----------
__global__ void k_wt(const void* __restrict__ cw, const void* __restrict__ sb,
                     ushort* __restrict__ wkt) {
    int isf = sniff_f32(sb);
    int bid = blockIdx.x;                      // 576 blocks
    int t = bid / 64, ib = (bid % 64) / 8, ob = bid % 8;
    __shared__ ushort tile[64][65];
    int tid = threadIdx.x;                     // 256 threads
    int oq = tid & 15, ir = tid >> 4;
#pragma unroll
    for (int p = 0; p < 4; ++p) {
        int i = p * 16 + ir;
        size_t off = ((size_t)(t * 512 + ib * 64 + i)) * 512 + ob * 64 + oq * 4;
        float v0, v1, v2, v3;
        if (isf) {
            float4 v = *(const float4*)((const float*)cw + off);
            v0 = v.x; v1 = v.y; v2 = v.z; v3 = v.w;
        } else {
            ushort4 v = *(const ushort4*)((const ushort*)cw + off);
            v0 = bf2f(v.x); v1 = bf2f(v.y); v2 = bf2f(v.z); v3 = bf2f(v.w);
        }
        tile[i][oq * 4 + 0] = f2bf(v0 * WSCALE);
        tile[i][oq * 4 + 1] = f2bf(v1 * WSCALE);
        tile[i][oq * 4 + 2] = f2bf(v2 * WSCALE);
        tile[i][oq * 4 + 3] = f2bf(v3 * WSCALE);
    }
    __syncthreads();
    int iq = tid & 15, orow = tid >> 4;
#pragma unroll
    for (int p = 0; p < 4; ++p) {
        int o = p * 16 + orow;
        ushort4 v;
        v.x = tile[iq * 4 + 0][o];
        v.y = tile[iq * 4 + 1][o];
        v.z = tile[iq * 4 + 2][o];
        v.w = tile[iq * 4 + 3][o];
        *(ushort4*)(wkt + ((size_t)(t * 512 + ob * 64 + o)) * 512 + ib * 64 + iq * 4) = v;
    }
}

// ---------------- demod from wkt: part[b][t][o] = sum_i (wkt*s)^2 ----------
__global__ void k_dmod(const ushort* __restrict__ wkt, const float* __restrict__ s,
                       float* __restrict__ part) {
    int t = blockIdx.x / 8, ob = blockIdx.x % 8;   // 72 blocks
    int tid = threadIdx.x;                          // 256 threads
    __shared__ float s2[4096];                      // [b][i]
    __shared__ float red[2048];                     // [ol][b][ks]
#pragma unroll
    for (int j = 0; j < 16; ++j) {
        int idx = j * 256 + tid;
        float v = s[idx];
        s2[idx] = v * v;
    }
    __syncthreads();
    int ol = tid >> 2, ks = tid & 3;
    int o = ob * 64 + ol;
    const ushort* row = wkt + (size_t)(t * 512 + o) * 512 + ks * 128;
    float acc[8] = {0, 0, 0, 0, 0, 0, 0, 0};
    for (int ch = 0; ch < 16; ++ch) {
        U16x8 wv; wv.v = *(const uint4*)(row + ch * 8);
        int ibase = ks * 128 + ch * 8;
#pragma unroll
        for (int e = 0; e < 8; ++e) {
            float wf = bf2f(wv.u[e]);
            float w2 = wf * wf;
#pragma unroll
            for (int b = 0; b < 8; ++b) acc[b] += w2 * s2[b * 512 + ibase + e];
        }
    }
#pragma unroll
    for (int b = 0; b < 8; ++b) red[(ol * 8 + b) * 4 + ks] = acc[b];
    __syncthreads();
#pragma unroll
    for (int p = 0; p < 2; ++p) {
        int q = tid * 2 + p;
        int ol2 = q >> 3, b2 = q & 7;
        float sum = red[q * 4 + 0] + red[q * 4 + 1] + red[q * 4 + 2] + red[q * 4 + 3];
        part[(b2 * 9 + t) * 512 + ob * 64 + ol2] = sum;
    }
}

__global__ void k_dfin(const float* __restrict__ part, float* __restrict__ d) {
    int gid = blockIdx.x * 256 + threadIdx.x;       // 16 x 256 = 4096
    int b = gid >> 9, o = gid & 511;
    float acc = 1e-8f;
#pragma unroll
    for (int t = 0; t < 9; ++t) acc += part[(b * 9 + t) * 512 + o];
    d[b * 512 + o] = rsqrtf(acc);
}

// ---------------- main conv v5: LDS-A halo + register-B pipeline -----------
#define GLL(gp, lp) __builtin_amdgcn_global_load_lds( \
    (const __attribute__((address_space(1))) void*)(gp), \
    (__attribute__((address_space(3))) void*)(lp), 16, 0, 0)

// load 4 B fragments (one k-half of one tap) into dst[0..3]
#define LOADB(dst, s_, c0_) { \
    size_t off_ = (size_t)((s_) >> 1) * 262144 + (c0_) + ((s_) & 1) * 32; \
    dst[0] = *(const bf16x8*)(bp0 + off_); \
    dst[1] = *(const bf16x8*)(bp1 + off_); \
    dst[2] = *(const bf16x8*)(bp2 + off_); \
    dst[3] = *(const bf16x8*)(bp3 + off_); }

__launch_bounds__(256, 3)
__global__ void k_conv(const ushort* __restrict__ xmp, const ushort* __restrict__ wkt,
                       const float* __restrict__ dmod, const void* __restrict__ noise,
                       const void* __restrict__ snoise, const void* __restrict__ bias_,
                       const void* __restrict__ sb, void* __restrict__ out) {
    __shared__ ushort Ah[4 * 66 * 64];          // 33792 B: [row][col][8 chunks]
    int isf = sniff_f32(sb);
    int b = blockIdx.z, rt = blockIdx.y, ct = blockIdx.x;
    int y0 = rt * 2, o0 = ct * 128;
    int tid = threadIdx.x;
    int lane = tid & 63, wv = tid >> 6;
    int wm = (wv >> 1) * 64, wn = (wv & 1) * 64;
    int quad = lane >> 4, lrow = lane & 15;
    const ushort* xb = xmp + (size_t)b * 66 * 66 * 512;

    // per-lane B base pointers (row = o, 16B chunk = quad)
    const ushort* bp0 = wkt + (size_t)(o0 + wn + 0 * 16 + lrow) * 512 + quad * 8;
    const ushort* bp1 = wkt + (size_t)(o0 + wn + 1 * 16 + lrow) * 512 + quad * 8;
    const ushort* bp2 = wkt + (size_t)(o0 + wn + 2 * 16 + lrow) * 512 + quad * 8;
    const ushort* bp3 = wkt + (size_t)(o0 + wn + 3 * 16 + lrow) * 512 + quad * 8;

    f32x4 acc[4][4] = {};
    bf16x8 bA[4], bB[4];

    auto stageA = [&](int c0a) {
#pragma unroll
        for (int it = 0; it < 8; ++it) {
            int L = it * 256 + tid;
            int cidx = L >> 3, slot = L & 7;
            int hrow = cidx / 66, col = cidx - hrow * 66;
            int kc = slot ^ (col & 7);
            GLL(xb + ((size_t)(y0 + hrow) * 66 + col) * 512 + c0a + kc * 8,
                (char*)Ah + L * 16);
        }
        if (wv == 0) {                          // tail 64 chunks, wave-uniform
            int L = 2048 + tid;
            int cidx = L >> 3, slot = L & 7;
            int hrow = cidx / 66, col = cidx - hrow * 66;
            int kc = slot ^ (col & 7);
            GLL(xb + ((size_t)(y0 + hrow) * 66 + col) * 512 + c0a + kc * 8,
                (char*)Ah + L * 16);
        }
    };

    LOADB(bA, 0, 0);                            // B pipe head (t=0,k0=0,c0=0)
    for (int c = 0; c < 8; ++c) {
        int c0 = c * 64;
        if (c) __syncthreads();                 // prev taps done reading Ah
        stageA(c0);
        __syncthreads();                        // halo staged
#pragma unroll
        for (int s = 0; s < 18; ++s) {
            // prefetch next B half-tap (rotation persists across c-chunks)
            if (s < 17) {
                if (s & 1) { LOADB(bA, s + 1, c0) } else { LOADB(bB, s + 1, c0) }
            } else if (c < 7) {
                if (s & 1) { LOADB(bA, 0, c0 + 64) } else { LOADB(bB, 0, c0 + 64) }
            }
            const bf16x8* Bc = (s & 1) ? bB : bA;
            int t = s >> 1, k0 = s & 1;
            int dy = t / 3 - 1, dx = t % 3 - 1;
            int hrow = (wv >> 1) + dy + 1;
            int ck = k0 * 4 + quad;
            bf16x8 afr[4];
#pragma unroll
            for (int am = 0; am < 4; ++am) {
                int col = am * 16 + lrow + dx + 1;
                afr[am] = *(const bf16x8*)((const char*)Ah +
                    (((hrow * 66 + col) << 3) + (ck ^ (col & 7))) * 16);
            }
#pragma unroll
            for (int am = 0; am < 4; ++am)
#pragma unroll
                for (int bn = 0; bn < 4; ++bn)
                    acc[am][bn] = __builtin_amdgcn_mfma_f32_16x16x32_bf16(
                        afr[am], Bc[bn], acc[am][bn], 0, 0, 0);
        }
    }

    // epilogue: y*d + sn*noise + bias -> lrelu(0.2)
    float dv[4], snv[4], bv[4];
#pragma unroll
    for (int bn = 0; bn < 4; ++bn) {
        int o = o0 + wn + bn * 16 + lrow;
        dv[bn] = dmod[b * 512 + o];
        snv[bn] = lda(snoise, o, isf);
        bv[bn] = lda(bias_, o, isf);
    }
#pragma unroll
    for (int am = 0; am < 4; ++am) {
#pragma unroll
        for (int r = 0; r < 4; ++r) {
            int m = wm + am * 16 + quad * 4 + r;  // C layout: row=quad*4+reg
            int yy = y0 + (m >> 6), xx = m & 63;
            float nz = lda(noise, (b * 64 + yy) * 64 + xx, isf);
            size_t obase = ((size_t)(b * 64 + yy) * 64 + xx) * 512;
            if (isf) {
                float* of = (float*)out;
#pragma unroll
                for (int bn = 0; bn < 4; ++bn) {
                    float v = acc[am][bn][r] * dv[bn] + snv[bn] * nz + bv[bn];
                    v = v > 0.f ? v : 0.2f * v;
                    of[obase + o0 + wn + bn * 16 + lrow] = v;
                }
            } else {
                ushort* ob = (ushort*)out;
#pragma unroll
                for (int bn = 0; bn < 4; ++bn) {
                    float v = acc[am][bn][r] * dv[bn] + snv[bn] * nz + bv[bn];
                    v = v > 0.f ? v : 0.2f * v;
                    ob[obase + o0 + wn + bn * 16 + lrow] = f2bf(v);
                }
            }
        }
    }
}

// ---------------- launch ---------------------------------------------------
extern "C" void kernel_launch(void* const* d_in, const int* in_sizes, int n_in,
                              void* d_out, int out_size, void* d_ws, size_t ws_size,
                              hipStream_t stream) {
    const void* x     = d_in[0];
    const void* w     = d_in[1];
    const void* noise = d_in[2];
    const void* sw    = d_in[3];
    const void* sb    = d_in[4];
    const void* cw    = d_in[5];
    const void* sn    = d_in[6];
    const void* bias  = d_in[7];

    char* ws = (char*)d_ws;
    ushort* xmp   = (ushort*)(ws);                // 8*66*66*512*2 = 35,684,352
    ushort* wkt   = (ushort*)(ws + 35684352);     // 9*512*512*2   =  4,718,592
    float*  s     = (float*)(ws + 40402944);      // 8*512*4
    float*  dmod  = (float*)(ws + 40419328);      // 8*512*4
    float*  part  = (float*)(ws + 40435712);      // 8*9*512*4     =    147,456
    float*  spart = (float*)(ws + 40583168);      // 8*8*512*4     =    131,072
    (void)in_sizes; (void)n_in; (void)out_size; (void)ws_size;

    hipLaunchKernelGGL(k_style_part, dim3(64),     dim3(512), 0, stream, w, sw, sb, spart);
    hipLaunchKernelGGL(k_style_fin,  dim3(8),      dim3(512), 0, stream, spart, sb, s);
    hipLaunchKernelGGL(k_wt,         dim3(576),    dim3(256), 0, stream, cw, sb, wkt);
    hipLaunchKernelGGL(k_dmod,       dim3(72),     dim3(256), 0, stream, wkt, s, part);
    hipLaunchKernelGGL(k_dfin,       dim3(16),     dim3(256), 0, stream, part, dmod);
    hipLaunchKernelGGL(k_pad,        dim3(8 * 66), dim3(256), 0, stream, x, s, sb, xmp);
    hipLaunchKernelGGL(k_conv,       dim3(4, 32, 8), dim3(256), 0, stream,
                       xmp, wkt, dmod, noise, sn, bias, sb, d_out);
}

// Round 6
// 330.801 us; speedup vs baseline: 1.7183x; 1.7183x over previous
//
#include <hip/hip_runtime.h>
#include <hip/hip_bf16.h>
#include <stdint.h>

// StyleGAN2 style block. B=8, H=W=64, Cin=Cout=512, wdim=512.
// Dtype-adaptive via sniff of style_bias[0].
// k_conv v6 = r3 backbone (A halo LDS + full-tap B dbuf via global_load_lds,
// 1 barrier/tap, XOR-swizzled conflict-free LDS) with:
//  - 32x32x16 bf16 MFMA (fewer issue cycles than 16x16x32)
//  - XCD-pinned ct decode (each XCD's L2 holds one 1.18MB wkt slice)
//  - cross-chunk B prefetch (global parity u=c*9+t, no exposed tap-0 stage)

typedef __attribute__((ext_vector_type(8))) __bf16 bf16x8;
typedef __attribute__((ext_vector_type(16))) float f32x16;

__device__ __forceinline__ float bf2f(ushort u) {
    union { uint32_t i; float f; } v; v.i = (uint32_t)u << 16; return v.f;
}
__device__ __forceinline__ ushort f2bf(float f) {
    union { float f; uint32_t i; } v; v.f = f;
    uint32_t r = v.i + 0x7fffu + ((v.i >> 16) & 1u);
    return (ushort)(r >> 16);
}
__device__ __forceinline__ int sniff_f32(const void* sb) {
    return ((const uint32_t*)sb)[0] == 0x3F800000u;
}
__device__ __forceinline__ float lda(const void* p, int idx, int isf) {
    return isf ? ((const float*)p)[idx] : bf2f(((const ushort*)p)[idx]);
}

union U16x8 { uint4 v; ushort u[8]; };

#define INV_SQRT_WDIM 0.04419417382415922f   /* 1/sqrt(512) */
#define SQRT2         1.4142135623730951f
#define WSCALE        0.014731391274719739f  /* 1/sqrt(9*512) */

// ---------------- style FC, split-K: part[b][ds][i] -----------------------
__global__ void k_style_part(const void* __restrict__ w, const void* __restrict__ sw,
                             const void* __restrict__ sb, float* __restrict__ part) {
    int isf = sniff_f32(sb);
    int b = blockIdx.x >> 3, ds = blockIdx.x & 7;   // 64 blocks
    int i = threadIdx.x;                             // 512 threads
    __shared__ float wrow[64];
    if (i < 64) wrow[i] = lda(w, b * 512 + ds * 64 + i, isf);
    __syncthreads();
    float acc = 0.f;
    if (isf) {
        const float* p = (const float*)sw + (size_t)ds * 64 * 512;
#pragma unroll 8
        for (int d = 0; d < 64; ++d) acc += wrow[d] * p[d * 512 + i];
    } else {
        const ushort* p = (const ushort*)sw + (size_t)ds * 64 * 512;
#pragma unroll 8
        for (int d = 0; d < 64; ++d) acc += wrow[d] * bf2f(p[d * 512 + i]);
    }
    part[(b * 8 + ds) * 512 + i] = acc;
}

__global__ void k_style_fin(const float* __restrict__ part, const void* __restrict__ sb,
                            float* __restrict__ s_out) {
    int isf = sniff_f32(sb);
    int b = blockIdx.x, i = threadIdx.x;             // 8 x 512
    float a = 0.f;
#pragma unroll
    for (int ds = 0; ds < 8; ++ds) a += part[(b * 8 + ds) * 512 + i];
    float s = a * INV_SQRT_WDIM + lda(sb, i, isf);
    s = (s > 0.f ? s : 0.2f * s) * SQRT2;
    s_out[b * 512 + i] = s;
}

// ---------------- padded modulated input: xmp[b][66][66][512] bf16 ---------
__global__ void k_pad(const void* __restrict__ x, const float* __restrict__ s,
                      const void* __restrict__ sb, ushort* __restrict__ xmp) {
    int isf = sniff_f32(sb);
    int pr = blockIdx.x;                       // 8*66 blocks
    int b = pr / 66, yp = pr % 66;
    int tid = threadIdx.x;                     // 256 threads
    ushort* rowp = xmp + ((size_t)b * 66 + yp) * 66 * 512;
    uint4 z = {0u, 0u, 0u, 0u};
    if (yp == 0 || yp == 65) {
        uint4* p = (uint4*)rowp;
        for (int l = tid; l < 66 * 512 * 2 / 16; l += 256) p[l] = z;
        return;
    }
    __shared__ float sv[512];
    for (int c = tid; c < 512; c += 256) sv[c] = s[b * 512 + c];
    if (tid < 64)       ((uint4*)rowp)[tid] = z;
    else if (tid < 128) ((uint4*)(rowp + 65 * 512))[tid - 64] = z;
    __syncthreads();
    int y = yp - 1;
    ushort* xout = rowp + 512;
    if (isf) {
        const float* xin = (const float*)x + ((size_t)b * 64 + y) * 64 * 512;
        for (int l = tid; l < 8192; l += 256) {
            int xi = l >> 7, cc = (l & 127) * 4;
            float4 in = *(const float4*)(xin + (size_t)xi * 512 + cc);
            ushort4 ov;
            ov.x = f2bf(in.x * sv[cc + 0]);
            ov.y = f2bf(in.y * sv[cc + 1]);
            ov.z = f2bf(in.z * sv[cc + 2]);
            ov.w = f2bf(in.w * sv[cc + 3]);
            *(ushort4*)(xout + (size_t)xi * 512 + cc) = ov;
        }
    } else {
        const ushort* xin = (const ushort*)x + ((size_t)b * 64 + y) * 64 * 512;
        for (int l = tid; l < 4096; l += 256) {
            int xi = l >> 6, cc = (l & 63) * 8;
            U16x8 in, ov;
            in.v = *(const uint4*)(xin + (size_t)xi * 512 + cc);
#pragma unroll
            for (int j = 0; j < 8; ++j) ov.u[j] = f2bf(bf2f(in.u[j]) * sv[cc + j]);
            *(uint4*)(xout + (size_t)xi * 512 + cc) = ov.v;
        }
    }
}

// ---------------- WkT[t][o][i] = cw[t][i][o] * 1/sqrt(4608), bf16 ----------
__global__ void k_wt(const void* __restrict__ cw, const void* __restrict__ sb,
                     ushort* __restrict__ wkt) {
    int isf = sniff_f32(sb);
    int bid = blockIdx.x;                      // 576 blocks
    int t = bid / 64, ib = (bid % 64) / 8, ob = bid % 8;
    __shared__ ushort tile[64][65];
    int tid = threadIdx.x;                     // 256 threads
    int oq = tid & 15, ir = tid >> 4;
#pragma unroll
    for (int p = 0; p < 4; ++p) {
        int i = p * 16 + ir;
        size_t off = ((size_t)(t * 512 + ib * 64 + i)) * 512 + ob * 64 + oq * 4;
        float v0, v1, v2, v3;
        if (isf) {
            float4 v = *(const float4*)((const float*)cw + off);
            v0 = v.x; v1 = v.y; v2 = v.z; v3 = v.w;
        } else {
            ushort4 v = *(const ushort4*)((const ushort*)cw + off);
            v0 = bf2f(v.x); v1 = bf2f(v.y); v2 = bf2f(v.z); v3 = bf2f(v.w);
        }
        tile[i][oq * 4 + 0] = f2bf(v0 * WSCALE);
        tile[i][oq * 4 + 1] = f2bf(v1 * WSCALE);
        tile[i][oq * 4 + 2] = f2bf(v2 * WSCALE);
        tile[i][oq * 4 + 3] = f2bf(v3 * WSCALE);
    }
    __syncthreads();
    int iq = tid & 15, orow = tid >> 4;
#pragma unroll
    for (int p = 0; p < 4; ++p) {
        int o = p * 16 + orow;
        ushort4 v;
        v.x = tile[iq * 4 + 0][o];
        v.y = tile[iq * 4 + 1][o];
        v.z = tile[iq * 4 + 2][o];
        v.w = tile[iq * 4 + 3][o];
        *(ushort4*)(wkt + ((size_t)(t * 512 + ob * 64 + o)) * 512 + ib * 64 + iq * 4) = v;
    }
}

// ---------------- demod from wkt: part[b][t][o] = sum_i (wkt*s)^2 ----------
__global__ void k_dmod(const ushort* __restrict__ wkt, const float* __restrict__ s,
                       float* __restrict__ part) {
    int t = blockIdx.x / 8, ob = blockIdx.x % 8;   // 72 blocks
    int tid = threadIdx.x;                          // 256 threads
    __shared__ float s2[4096];                      // [b][i]
    __shared__ float red[2048];                     // [ol][b][ks]
#pragma unroll
    for (int j = 0; j < 16; ++j) {
        int idx = j * 256 + tid;
        float v = s[idx];
        s2[idx] = v * v;
    }
    __syncthreads();
    int ol = tid >> 2, ks = tid & 3;
    int o = ob * 64 + ol;
    const ushort* row = wkt + (size_t)(t * 512 + o) * 512 + ks * 128;
    float acc[8] = {0, 0, 0, 0, 0, 0, 0, 0};
    for (int ch = 0; ch < 16; ++ch) {
        U16x8 wv; wv.v = *(const uint4*)(row + ch * 8);
        int ibase = ks * 128 + ch * 8;
#pragma unroll
        for (int e = 0; e < 8; ++e) {
            float wf = bf2f(wv.u[e]);
            float w2 = wf * wf;
#pragma unroll
            for (int b = 0; b < 8; ++b) acc[b] += w2 * s2[b * 512 + ibase + e];
        }
    }
#pragma unroll
    for (int b = 0; b < 8; ++b) red[(ol * 8 + b) * 4 + ks] = acc[b];
    __syncthreads();
#pragma unroll
    for (int p = 0; p < 2; ++p) {
        int q = tid * 2 + p;
        int ol2 = q >> 3, b2 = q & 7;
        float sum = red[q * 4 + 0] + red[q * 4 + 1] + red[q * 4 + 2] + red[q * 4 + 3];
        part[(b2 * 9 + t) * 512 + ob * 64 + ol2] = sum;
    }
}

__global__ void k_dfin(const float* __restrict__ part, float* __restrict__ d) {
    int gid = blockIdx.x * 256 + threadIdx.x;       // 16 x 256 = 4096
    int b = gid >> 9, o = gid & 511;
    float acc = 1e-8f;
#pragma unroll
    for (int t = 0; t < 9; ++t) acc += part[(b * 9 + t) * 512 + o];
    d[b * 512 + o] = rsqrtf(acc);
}

// ---------------- main conv v6 --------------------------------------------
#define GLL(gp, lp) __builtin_amdgcn_global_load_lds( \
    (const __attribute__((address_space(1))) void*)(gp), \
    (__attribute__((address_space(3))) void*)(lp), 16, 0, 0)

__launch_bounds__(256, 2)
__global__ void k_conv(const ushort* __restrict__ xmp, const ushort* __restrict__ wkt,
                       const float* __restrict__ dmod, const void* __restrict__ noise,
                       const void* __restrict__ snoise, const void* __restrict__ bias_,
                       const void* __restrict__ sb, void* __restrict__ out) {
    __shared__ ushort Ah[4 * 66 * 64];          // 33792 B: [row][col][8 slots]
    __shared__ ushort Bl[2][128 * 64];          // 2 x 16384 B: [row][8 slots]
    int isf = sniff_f32(sb);
    int id = blockIdx.x;                        // 1024; id%8 pins XCD -> ct
    int ct = id & 3;
    int rt = (id >> 2) & 31;
    int b  = id >> 7;
    int y0 = rt * 2, o0 = ct * 128;
    int tid = threadIdx.x;
    int lane = tid & 63, wv = tid >> 6;
    int wm = (wv >> 1) * 64, wn = (wv & 1) * 64;
    int lm = lane & 31, kh = lane >> 5;         // 32x32 lane decomposition
    const ushort* xb = xmp + (size_t)b * 66 * 66 * 512;
    const ushort* wkt_o0 = wkt + (size_t)o0 * 512;

    // B staging per-thread constants (4 rounds of 256 x 16B = 16 KB)
    f32x16 acc[2][2] = {};

    auto stageA = [&](int c0a) {
#pragma unroll
        for (int it = 0; it < 8; ++it) {
            int L = it * 256 + tid;
            int cidx = L >> 3, slot = L & 7;
            int hrow = cidx / 66, col = cidx - hrow * 66;
            int kc = slot ^ (col & 7);
            GLL(xb + ((size_t)(y0 + hrow) * 66 + col) * 512 + c0a + kc * 8,
                (char*)Ah + L * 16);
        }
        if (wv == 0) {                          // tail 64 chunks, wave-uniform
            int L = 2048 + tid;
            int cidx = L >> 3, slot = L & 7;
            int hrow = cidx / 66, col = cidx - hrow * 66;
            int kc = slot ^ (col & 7);
            GLL(xb + ((size_t)(y0 + hrow) * 66 + col) * 512 + c0a + kc * 8,
                (char*)Ah + L * 16);
        }
    };
    auto stageB = [&](int tap, int c0b, char* dst) {
#pragma unroll
        for (int it = 0; it < 4; ++it) {
            int L = it * 256 + tid;
            int row = L >> 3, slot = L & 7;
            int kc = slot ^ (row & 7);
            GLL(wkt_o0 + (size_t)tap * 262144 + (size_t)row * 512 + c0b + kc * 8,
                dst + L * 16);
        }
    };

    stageB(0, 0, (char*)Bl[0]);                 // pipe head: u=0
    int u = 0;
    for (int c = 0; c < 8; ++c) {
        int c0 = c * 64;
        if (c) __syncthreads();                 // taps of c-1 done reading Ah
        stageA(c0);
        __syncthreads();                        // halo (and pending B) staged
        for (int t = 0; t < 9; ++t, ++u) {
            // prefetch B for u+1 into the other buffer
            if (t < 8)      stageB(t + 1, c0, (char*)Bl[(u + 1) & 1]);
            else if (c < 7) stageB(0, c0 + 64, (char*)Bl[(u + 1) & 1]);
            int dy = t / 3 - 1, dx = t % 3 - 1;
            int hrow = (wv >> 1) + dy + 1;
            const char* bb = (const char*)Bl[u & 1];
#pragma unroll
            for (int ks = 0; ks < 4; ++ks) {
                int ck = ks * 2 + kh;           // 16B chunk index (8 ch)
                bf16x8 afr[2], bfr[2];
#pragma unroll
                for (int am = 0; am < 2; ++am) {
                    int col = am * 32 + lm + dx + 1;
                    afr[am] = *(const bf16x8*)((const char*)Ah +
                        (((hrow * 66 + col) << 3) + (ck ^ (col & 7))) * 16);
                }
#pragma unroll
                for (int bn = 0; bn < 2; ++bn) {
                    int row = wn + bn * 32 + lm;
                    bfr[bn] = *(const bf16x8*)(bb +
                        ((row << 3) + (ck ^ (row & 7))) * 16);
                }
#pragma unroll
                for (int am = 0; am < 2; ++am)
#pragma unroll
                    for (int bn = 0; bn < 2; ++bn)
                        acc[am][bn] = __builtin_amdgcn_mfma_f32_32x32x16_bf16(
                            afr[am], bfr[bn], acc[am][bn], 0, 0, 0);
            }
            __syncthreads();                    // drains prefetch for u+1
        }
    }

    // epilogue: y*d + sn*noise + bias -> lrelu(0.2)
    // 32x32 C layout: col = lane&31 (o), row = (reg&3) + 8*(reg>>2) + 4*kh (m)
    float dv[2], snv[2], bv[2];
#pragma unroll
    for (int bn = 0; bn < 2; ++bn) {
        int o = o0 + wn + bn * 32 + lm;
        dv[bn] = dmod[b * 512 + o];
        snv[bn] = lda(snoise, o, isf);
        bv[bn] = lda(bias_, o, isf);
    }
#pragma unroll
    for (int am = 0; am < 2; ++am) {
#pragma unroll
        for (int reg = 0; reg < 16; ++reg) {
            int p = wm + am * 32 + 4 * kh + (reg & 3) + 8 * (reg >> 2);
            int yy = y0 + (p >> 6), xx = p & 63;
            float nz = lda(noise, (b * 64 + yy) * 64 + xx, isf);
            size_t obase = ((size_t)(b * 64 + yy) * 64 + xx) * 512;
            if (isf) {
                float* of = (float*)out;
#pragma unroll
                for (int bn = 0; bn < 2; ++bn) {
                    float v = acc[am][bn][reg] * dv[bn] + snv[bn] * nz + bv[bn];
                    v = v > 0.f ? v : 0.2f * v;
                    of[obase + o0 + wn + bn * 32 + lm] = v;
                }
            } else {
                ushort* ob = (ushort*)out;
#pragma unroll
                for (int bn = 0; bn < 2; ++bn) {
                    float v = acc[am][bn][reg] * dv[bn] + snv[bn] * nz + bv[bn];
                    v = v > 0.f ? v : 0.2f * v;
                    ob[obase + o0 + wn + bn * 32 + lm] = f2bf(v);
                }
            }
        }
    }
}

// ---------------- launch ---------------------------------------------------
extern "C" void kernel_launch(void* const* d_in, const int* in_sizes, int n_in,
                              void* d_out, int out_size, void* d_ws, size_t ws_size,
                              hipStream_t stream) {
    const void* x     = d_in[0];
    const void* w     = d_in[1];
    const void* noise = d_in[2];
    const void* sw    = d_in[3];
    const void* sb    = d_in[4];
    const void* cw    = d_in[5];
    const void* sn    = d_in[6];
    const void* bias  = d_in[7];

    char* ws = (char*)d_ws;
    ushort* xmp   = (ushort*)(ws);                // 8*66*66*512*2 = 35,684,352
    ushort* wkt   = (ushort*)(ws + 35684352);     // 9*512*512*2   =  4,718,592
    float*  s     = (float*)(ws + 40402944);      // 8*512*4
    float*  dmod  = (float*)(ws + 40419328);      // 8*512*4
    float*  part  = (float*)(ws + 40435712);      // 8*9*512*4     =    147,456
    float*  spart = (float*)(ws + 40583168);      // 8*8*512*4     =    131,072
    (void)in_sizes; (void)n_in; (void)out_size; (void)ws_size;

    hipLaunchKernelGGL(k_style_part, dim3(64),     dim3(512), 0, stream, w, sw, sb, spart);
    hipLaunchKernelGGL(k_style_fin,  dim3(8),      dim3(512), 0, stream, spart, sb, s);
    hipLaunchKernelGGL(k_wt,         dim3(576),    dim3(256), 0, stream, cw, sb, wkt);
    hipLaunchKernelGGL(k_dmod,       dim3(72),     dim3(256), 0, stream, wkt, s, part);
    hipLaunchKernelGGL(k_dfin,       dim3(16),     dim3(256), 0, stream, part, dmod);
    hipLaunchKernelGGL(k_pad,        dim3(8 * 66), dim3(256), 0, stream, x, s, sb, xmp);
    hipLaunchKernelGGL(k_conv,       dim3(1024),   dim3(256), 0, stream,
                       xmp, wkt, dmod, noise, sn, bias, sb, d_out);
}